// Round 3
// baseline (146.586 us; speedup 1.0000x reference)
//
#include <hip/hip_runtime.h>

// Problem constants (match reference)
constexpr int   Bsz = 32, Csz = 8, Hsz = 256, Wsz = 256;
constexpr int   HW  = Hsz * Wsz;            // 65536 pixels per plane
constexpr int   G   = Csz / 4;              // 2 groups
constexpr int   NBG = Bsz * G;              // 64 (b,g) slots
constexpr float MASK_WEIGHT = 0.7f;
constexpr float IM_WEIGHT   = 0.3f;
// sigmoid(x) > 0.7  <=>  x > ln(0.7/0.3)
constexpr float XTHRESH = 0.8472978603872037f;

constexpr int BLK   = 256;
constexpr int ITERS = 4;                                  // float4 groups per thread per plane
constexpr int PIX4_PER_BG   = HW / 4;                     // 16384 float4 per plane
constexpr int BLOCKS_PER_BG = PIX4_PER_BG / (BLK * ITERS);// 16
constexpr int NB = NBG * BLOCKS_PER_BG;                   // 1024 blocks (4 per CU)

// ws float layout (block-private slots -> no zero-init, no atomics):
//   [0..NB)      bce partial per block
//   [NB..2NB)    masked-norm sum partial
//   [2NB..3NB)   masked count partial
//   [3NB..4NB)   diff_norm sum partial (fallback)

__device__ __forceinline__ float get(const float4& v, int e) {
    return e == 0 ? v.x : e == 1 ? v.y : e == 2 ? v.z : v.w;
}

__global__ __launch_bounds__(256) void lp_mask_main(
    const float* __restrict__ out, const float* __restrict__ tar,
    float* __restrict__ ws)
{
    const int tid   = threadIdx.x;
    const int blk   = blockIdx.x;
    const int bg    = blk / BLOCKS_PER_BG;      // 0..63 (= b*G + g)
    const int chunk = blk % BLOCKS_PER_BG;

    // channel base: (b*C + g*4) * HW == bg * 4 * HW
    const size_t base = (size_t)bg * 4 * HW;
    const float4* po = reinterpret_cast<const float4*>(out + base);
    const float4* pt = reinterpret_cast<const float4*>(tar + base);
    constexpr int P4 = HW / 4;                  // float4 per plane

    float bce = 0.0f, msum = 0.0f, cnt = 0.0f, dsum = 0.0f;

    constexpr float LOG2E = 1.4426950408889634f;
    constexpr float LN2   = 0.6931471805599453f;

    const int idx0 = chunk * (BLK * ITERS) + tid;

    // Double-buffered register pipeline: keep the next iteration's 8 float4
    // loads (8 KB/wave) in flight across the current iteration's compute.
    float4 bufA[8], bufB[8];

#define LD8(dst, idx)                                                   \
    do {                                                                \
        (dst)[0] = po[(idx)];            (dst)[1] = po[(idx) + P4];     \
        (dst)[2] = po[(idx) + 2 * P4];   (dst)[3] = po[(idx) + 3 * P4]; \
        (dst)[4] = pt[(idx)];            (dst)[5] = pt[(idx) + P4];     \
        (dst)[6] = pt[(idx) + 2 * P4];   (dst)[7] = pt[(idx) + 3 * P4]; \
    } while (0)

    LD8(bufA, idx0);

#pragma unroll
    for (int it = 0; it < ITERS; ++it) {
        float4* C = (it & 1) ? bufB : bufA;
        float4* N = (it & 1) ? bufA : bufB;
        if (it + 1 < ITERS) {
            const int idxn = idx0 + (it + 1) * BLK;
            LD8(N, idxn);
        }

#pragma unroll
        for (int e = 0; e < 4; ++e) {
            const float x  = get(C[3], e);      // mask logit
            const float t  = get(C[7], e);      // mask target
            const float d0 = get(C[0], e) - get(C[4], e);
            const float d1 = get(C[1], e) - get(C[5], e);
            const float d2 = get(C[2], e) - get(C[6], e);

            // t*log(sig(x)) + (1-t)*log(1-sig(x)) = t*x - softplus(x)
            const float ax = __builtin_fabsf(x);
            const float ex = __builtin_exp2f(-ax * LOG2E);            // exp(-|x|)
            const float sp = fmaxf(x, 0.0f) + __builtin_log2f(1.0f + ex) * LN2;
            bce += __builtin_fmaf(t, x, -sp);

            const float dn = __builtin_sqrtf(d0 * d0 + d1 * d1 + d2 * d2);
            dsum += dn;
            if (x > XTHRESH) {
                msum += dn;
                cnt  += (dn != 0.0f) ? 1.0f : 0.0f;
            }
        }
    }
#undef LD8

    // wave (64-lane) reduction
#pragma unroll
    for (int off = 32; off > 0; off >>= 1) {
        bce  += __shfl_down(bce,  off, 64);
        msum += __shfl_down(msum, off, 64);
        cnt  += __shfl_down(cnt,  off, 64);
        dsum += __shfl_down(dsum, off, 64);
    }

    __shared__ float s[4][4];                   // 4 waves x 4 quantities
    const int wave = tid >> 6, lane = tid & 63;
    if (lane == 0) {
        s[wave][0] = bce; s[wave][1] = msum; s[wave][2] = cnt; s[wave][3] = dsum;
    }
    __syncthreads();
    if (tid == 0) {
        float rb = 0.0f, rm = 0.0f, rc = 0.0f, rd = 0.0f;
#pragma unroll
        for (int w = 0; w < 4; ++w) {
            rb += s[w][0]; rm += s[w][1]; rc += s[w][2]; rd += s[w][3];
        }
        ws[blk]          = rb;                  // block-private: no atomics
        ws[NB + blk]     = rm;
        ws[2 * NB + blk] = rc;
        ws[3 * NB + blk] = rd;
    }
}

__global__ __launch_bounds__(64) void lp_mask_final(
    const float* __restrict__ ws, float* __restrict__ outp)
{
    const int t = threadIdx.x;                  // one thread per (b,g), 64 total
    // This thread's 16 consecutive block-partials per quantity; float4 reads.
    constexpr int NPB = BLOCKS_PER_BG;          // 16
    const float4* wb = reinterpret_cast<const float4*>(ws) + t * (NPB / 4);
    const float4* wm = reinterpret_cast<const float4*>(ws + NB) + t * (NPB / 4);
    const float4* wc = reinterpret_cast<const float4*>(ws + 2 * NB) + t * (NPB / 4);
    const float4* wd = reinterpret_cast<const float4*>(ws + 3 * NB) + t * (NPB / 4);

    float b = 0.0f, m = 0.0f, c = 0.0f, d = 0.0f;
#pragma unroll
    for (int i = 0; i < NPB / 4; ++i) {
        const float4 vb = wb[i], vm = wm[i], vc = wc[i], vd = wd[i];
        b += vb.x + vb.y + vb.z + vb.w;
        m += vm.x + vm.y + vm.z + vm.w;
        c += vc.x + vc.y + vc.z + vc.w;
        d += vd.x + vd.y + vd.z + vd.w;
    }

    float ps = (c > 0.0f) ? (m / fmaxf(c, 1.0f)) : (d / (float)HW);

#pragma unroll
    for (int off = 32; off > 0; off >>= 1) {
        ps += __shfl_down(ps, off, 64);
        b  += __shfl_down(b,  off, 64);
    }

    if (t == 0) {
        // mean_g mask_loss = -bce_total / (G*B*HW); mean_g nocs = sum_ps / (B*G)
        const float mask_mean = -b / ((float)G * (float)Bsz * (float)HW);
        const float nocs_mean = ps / (float)(Bsz * G);
        outp[0] = MASK_WEIGHT * mask_mean + IM_WEIGHT * nocs_mean;
    }
}

extern "C" void kernel_launch(void* const* d_in, const int* in_sizes, int n_in,
                              void* d_out, int out_size, void* d_ws, size_t ws_size,
                              hipStream_t stream) {
    const float* out = (const float*)d_in[0];
    const float* tar = (const float*)d_in[1];
    float* ws = (float*)d_ws;
    float* o  = (float*)d_out;

    lp_mask_main<<<NB, BLK, 0, stream>>>(out, tar, ws);
    lp_mask_final<<<1, 64, 0, stream>>>(ws, o);
}

// Round 5
// 139.586 us; speedup vs baseline: 1.0501x; 1.0501x over previous
//
#include <hip/hip_runtime.h>

// Problem constants (match reference)
constexpr int   Bsz = 32, Csz = 8, Hsz = 256, Wsz = 256;
constexpr int   HW  = Hsz * Wsz;            // 65536 pixels per plane
constexpr int   G   = Csz / 4;              // 2 groups
constexpr int   NBG = Bsz * G;              // 64 (b,g) slots
constexpr float MASK_WEIGHT = 0.7f;
constexpr float IM_WEIGHT   = 0.3f;
// sigmoid(x) > 0.7  <=>  x > ln(0.7/0.3)
constexpr float XTHRESH = 0.8472978603872037f;

constexpr int BLK   = 256;
constexpr int ITERS = 2;                                  // float4 groups per thread per plane
constexpr int PIX4_PER_BG   = HW / 4;                     // 16384 float4 per plane
constexpr int BLOCKS_PER_BG = PIX4_PER_BG / (BLK * ITERS);// 32
constexpr int NB = NBG * BLOCKS_PER_BG;                   // 2048 blocks (8 per CU)

// Native clang vector type: __builtin_nontemporal_load requires a pointer to
// scalar or vector-of-scalar, not HIP's float4 struct.
typedef float fvec4 __attribute__((ext_vector_type(4)));

// ws float layout (block-private slots -> no zero-init, no atomics):
//   [0..NB)      bce partial per block
//   [NB..2NB)    masked-norm sum partial
//   [2NB..3NB)   masked count partial
//   [3NB..4NB)   diff_norm sum partial (fallback)

__global__ __launch_bounds__(256) void lp_mask_main(
    const float* __restrict__ out, const float* __restrict__ tar,
    float* __restrict__ ws)
{
    const int tid   = threadIdx.x;
    const int blk   = blockIdx.x;
    const int bg    = blk / BLOCKS_PER_BG;      // 0..63 (= b*G + g)
    const int chunk = blk % BLOCKS_PER_BG;

    // channel base: (b*C + g*4) * HW == bg * 4 * HW
    const size_t base = (size_t)bg * 4 * HW;
    const fvec4* po = reinterpret_cast<const fvec4*>(out + base);
    const fvec4* pt = reinterpret_cast<const fvec4*>(tar + base);
    constexpr int P4 = HW / 4;                  // float4 per plane

    float bce = 0.0f, msum = 0.0f, cnt = 0.0f, dsum = 0.0f;

    constexpr float LOG2E = 1.4426950408889634f;
    constexpr float LN2   = 0.6931471805599453f;

#pragma unroll
    for (int it = 0; it < ITERS; ++it) {
        const int idx = chunk * (BLK * ITERS) + it * BLK + tid;
        // Non-temporal: data is touched exactly once; skip L1 allocation
        // (testing whether the vL1D fill path is the ~3 TB/s choke).
        const fvec4 a0 = __builtin_nontemporal_load(&po[idx]);
        const fvec4 a1 = __builtin_nontemporal_load(&po[idx + P4]);
        const fvec4 a2 = __builtin_nontemporal_load(&po[idx + 2 * P4]);
        const fvec4 a3 = __builtin_nontemporal_load(&po[idx + 3 * P4]);
        const fvec4 b0 = __builtin_nontemporal_load(&pt[idx]);
        const fvec4 b1 = __builtin_nontemporal_load(&pt[idx + P4]);
        const fvec4 b2 = __builtin_nontemporal_load(&pt[idx + 2 * P4]);
        const fvec4 b3 = __builtin_nontemporal_load(&pt[idx + 3 * P4]);

#pragma unroll
        for (int e = 0; e < 4; ++e) {
            const float x  = a3[e];             // mask logit
            const float t  = b3[e];             // mask target
            const float d0 = a0[e] - b0[e];
            const float d1 = a1[e] - b1[e];
            const float d2 = a2[e] - b2[e];

            // t*log(sig(x)) + (1-t)*log(1-sig(x)) = t*x - softplus(x)
            const float ax = __builtin_fabsf(x);
            const float ex = __builtin_exp2f(-ax * LOG2E);            // exp(-|x|)
            const float sp = fmaxf(x, 0.0f) + __builtin_log2f(1.0f + ex) * LN2;
            bce += __builtin_fmaf(t, x, -sp);

            const float dn = __builtin_sqrtf(d0 * d0 + d1 * d1 + d2 * d2);
            dsum += dn;
            if (x > XTHRESH) {
                msum += dn;
                cnt  += (dn != 0.0f) ? 1.0f : 0.0f;
            }
        }
    }

    // wave (64-lane) reduction
#pragma unroll
    for (int off = 32; off > 0; off >>= 1) {
        bce  += __shfl_down(bce,  off, 64);
        msum += __shfl_down(msum, off, 64);
        cnt  += __shfl_down(cnt,  off, 64);
        dsum += __shfl_down(dsum, off, 64);
    }

    __shared__ float s[4][4];                   // 4 waves x 4 quantities
    const int wave = tid >> 6, lane = tid & 63;
    if (lane == 0) {
        s[wave][0] = bce; s[wave][1] = msum; s[wave][2] = cnt; s[wave][3] = dsum;
    }
    __syncthreads();
    if (tid == 0) {
        float rb = 0.0f, rm = 0.0f, rc = 0.0f, rd = 0.0f;
#pragma unroll
        for (int w = 0; w < 4; ++w) {
            rb += s[w][0]; rm += s[w][1]; rc += s[w][2]; rd += s[w][3];
        }
        ws[blk]          = rb;                  // block-private: no atomics
        ws[NB + blk]     = rm;
        ws[2 * NB + blk] = rc;
        ws[3 * NB + blk] = rd;
    }
}

__global__ __launch_bounds__(64) void lp_mask_final(
    const float* __restrict__ ws, float* __restrict__ outp)
{
    const int t = threadIdx.x;                  // one thread per (b,g), 64 total
    // This thread's 32 consecutive block-partials per quantity; float4 reads.
    constexpr int NPB = BLOCKS_PER_BG;          // 32
    const fvec4* wb = reinterpret_cast<const fvec4*>(ws) + t * (NPB / 4);
    const fvec4* wm = reinterpret_cast<const fvec4*>(ws + NB) + t * (NPB / 4);
    const fvec4* wc = reinterpret_cast<const fvec4*>(ws + 2 * NB) + t * (NPB / 4);
    const fvec4* wd = reinterpret_cast<const fvec4*>(ws + 3 * NB) + t * (NPB / 4);

    float b = 0.0f, m = 0.0f, c = 0.0f, d = 0.0f;
#pragma unroll
    for (int i = 0; i < NPB / 4; ++i) {
        const fvec4 vb = wb[i], vm = wm[i], vc = wc[i], vd = wd[i];
        b += vb[0] + vb[1] + vb[2] + vb[3];
        m += vm[0] + vm[1] + vm[2] + vm[3];
        c += vc[0] + vc[1] + vc[2] + vc[3];
        d += vd[0] + vd[1] + vd[2] + vd[3];
    }

    float ps = (c > 0.0f) ? (m / fmaxf(c, 1.0f)) : (d / (float)HW);

#pragma unroll
    for (int off = 32; off > 0; off >>= 1) {
        ps += __shfl_down(ps, off, 64);
        b  += __shfl_down(b,  off, 64);
    }

    if (t == 0) {
        // mean_g mask_loss = -bce_total / (G*B*HW); mean_g nocs = sum_ps / (B*G)
        const float mask_mean = -b / ((float)G * (float)Bsz * (float)HW);
        const float nocs_mean = ps / (float)(Bsz * G);
        outp[0] = MASK_WEIGHT * mask_mean + IM_WEIGHT * nocs_mean;
    }
}

extern "C" void kernel_launch(void* const* d_in, const int* in_sizes, int n_in,
                              void* d_out, int out_size, void* d_ws, size_t ws_size,
                              hipStream_t stream) {
    const float* out = (const float*)d_in[0];
    const float* tar = (const float*)d_in[1];
    float* ws = (float*)d_ws;
    float* o  = (float*)d_out;

    lp_mask_main<<<NB, BLK, 0, stream>>>(out, tar, ws);
    lp_mask_final<<<1, 64, 0, stream>>>(ws, o);
}